// Round 1
// baseline (167.821 us; speedup 1.0000x reference)
//
#include <hip/hip_runtime.h>

typedef float f32x4 __attribute__((ext_vector_type(4)));
typedef __bf16 bf16x8 __attribute__((ext_vector_type(8)));
typedef __bf16 bf16x4 __attribute__((ext_vector_type(4)));

#define MFMA16(a, b, c) __builtin_amdgcn_mfma_f32_16x16x32_bf16((a), (b), (c), 0, 0, 0)

constexpr int Bn = 4, Tn = 4096, Cn = 512, Hn = 64;
// fold C^-0.5 (NOTE: reference scales by n_embed^-0.5, not head^-0.5) and log2(e)
// into Wq so attention softmax is pure exp2.
constexpr float QSCALE = 1.4426950408889634f * 0.04419417382415922f;

// ---------------- kernel 0: W fp32 -> bf16 (Wq pre-scaled) ----------------
__global__ void wconv(const float* __restrict__ Wq, const float* __restrict__ Wk,
                      const float* __restrict__ Wv, __bf16* __restrict__ Wb) {
    int t = blockIdx.y;
    int i = blockIdx.x * 256 + threadIdx.x;  // 0..32767
    const float* src = (t == 0) ? Wq : (t == 1) ? Wk : Wv;
    float scale = (t == 0) ? QSCALE : 1.0f;
    Wb[t * Hn * Cn + i] = (__bf16)(src[i] * scale);
}

__device__ inline bf16x8 cvt8(float4 u0, float4 u1) {
    bf16x8 r;
    r[0] = (__bf16)u0.x; r[1] = (__bf16)u0.y; r[2] = (__bf16)u0.z; r[3] = (__bf16)u0.w;
    r[4] = (__bf16)u1.x; r[5] = (__bf16)u1.y; r[6] = (__bf16)u1.z; r[7] = (__bf16)u1.w;
    return r;
}

// ---------------- kernel 1: fused QKV projection (gemm_bt pattern) --------
// 1 wave per block, 32 rows per wave. Q,K stored row-major [16384][64] bf16;
// V stored transposed [B][64][T] bf16 so PV B-fragments are contiguous.
__global__ __launch_bounds__(64) void proj(const float* __restrict__ x,
                                           const __bf16* __restrict__ Wb,
                                           __bf16* __restrict__ Qb,
                                           __bf16* __restrict__ Kb,
                                           __bf16* __restrict__ VT) {
    const int lane = threadIdx.x;
    const int c = lane & 15, h = lane >> 4;
    const int row0 = blockIdx.x * 32;

    f32x4 acc[3][4][2] = {};
    const float* xr0 = x + (size_t)(row0 + c) * Cn;
    const float* xr1 = x + (size_t)(row0 + 16 + c) * Cn;

#pragma unroll
    for (int ks = 0; ks < 16; ++ks) {
        const int kb = ks * 32 + 8 * h;
        const float4* p0 = (const float4*)(xr0 + kb);
        const float4* p1 = (const float4*)(xr1 + kb);
        bf16x8 a0 = cvt8(p0[0], p0[1]);
        bf16x8 a1 = cvt8(p1[0], p1[1]);
#pragma unroll
        for (int w = 0; w < 3; ++w) {
#pragma unroll
            for (int nt = 0; nt < 4; ++nt) {
                bf16x8 bf = *(const bf16x8*)(Wb + (size_t)(w * Hn + nt * 16 + c) * Cn + kb);
                acc[w][nt][0] = MFMA16(a0, bf, acc[w][nt][0]);
                acc[w][nt][1] = MFMA16(a1, bf, acc[w][nt][1]);
            }
        }
    }

    // Q, K epilogue: LDS transpose -> coalesced row-major stores.
    __shared__ __bf16 lds[32][72];
#pragma unroll
    for (int w = 0; w < 2; ++w) {
        __syncthreads();
#pragma unroll
        for (int nt = 0; nt < 4; ++nt)
#pragma unroll
            for (int rt = 0; rt < 2; ++rt)
#pragma unroll
                for (int r = 0; r < 4; ++r)
                    lds[rt * 16 + h * 4 + r][nt * 16 + c] = (__bf16)acc[w][nt][rt][r];
        __syncthreads();
        __bf16* dst = (w == 0) ? Qb : Kb;
#pragma unroll
        for (int ch = 0; ch < 4; ++ch) {
            int rr = ch * 8 + (lane >> 3);
            bf16x8 vv = *(const bf16x8*)(&lds[rr][(lane & 7) * 8]);
            *(bf16x8*)(dst + (size_t)(row0 + rr) * Hn + (lane & 7) * 8) = vv;
        }
    }

    // V epilogue: direct transposed store (lane holds 4 consecutive tokens).
    const int b = row0 >> 12;
    const int t0 = row0 & (Tn - 1);
#pragma unroll
    for (int nt = 0; nt < 4; ++nt)
#pragma unroll
        for (int rt = 0; rt < 2; ++rt) {
            f32x4 a = acc[2][nt][rt];
            bf16x4 v4;
            v4[0] = (__bf16)a.x; v4[1] = (__bf16)a.y;
            v4[2] = (__bf16)a.z; v4[3] = (__bf16)a.w;
            *(bf16x4*)(VT + (size_t)(b * Hn + nt * 16 + c) * Tn + t0 + rt * 16 + h * 4) = v4;
        }
}

// ---------------- kernel 2: causal flash attention ------------------------
// 1 wave per block = 16 q rows; KBLK=64; K/VT fragments straight from global
// (L2-resident, 4MB total). LPT ordering: longest q-tiles launch first.
__global__ __launch_bounds__(64) void attn(const __bf16* __restrict__ Qb,
                                           const __bf16* __restrict__ Kb,
                                           const __bf16* __restrict__ VT,
                                           float* __restrict__ out) {
    const int lane = threadIdx.x;
    const int c = lane & 15, h = lane >> 4;
    const int i = blockIdx.x;
    const int qt = (Tn / 16 - 1) - (i >> 2);  // 255..0, longest first
    const int b = i & 3;

    const __bf16* Kbase = Kb + (size_t)b * Tn * Hn;
    const __bf16* Vbase = VT + (size_t)b * Hn * Tn;

    const size_t qrow = (size_t)b * Tn + qt * 16 + c;
    const bf16x8 qf0 = *(const bf16x8*)(Qb + qrow * Hn + 8 * h);
    const bf16x8 qf1 = *(const bf16x8*)(Qb + qrow * Hn + 32 + 8 * h);

    f32x4 o[4] = {};
    float m[4] = {-1e30f, -1e30f, -1e30f, -1e30f};
    float l[4] = {0.f, 0.f, 0.f, 0.f};

    __shared__ __bf16 pl[16][72];

    const int nkv = qt / 4 + 1;
    const int irow = qt * 16 + h * 4;

    for (int kt = 0; kt < nkv; ++kt) {
        const int j0 = kt * 64;
        // S = Q K^T  (S frag: col = kv = lane&15, row = q = 4h+r)
        f32x4 s[4];
#pragma unroll
        for (int ct = 0; ct < 4; ++ct) {
            const __bf16* kp = Kbase + (size_t)(j0 + ct * 16 + c) * Hn;
            f32x4 z = {};
            z = MFMA16(qf0, *(const bf16x8*)(kp + 8 * h), z);
            z = MFMA16(qf1, *(const bf16x8*)(kp + 32 + 8 * h), z);
            s[ct] = z;
        }
        // causal mask (diagonal tiles only; wave-uniform branch)
        if (j0 + 63 > qt * 16) {
#pragma unroll
            for (int ct = 0; ct < 4; ++ct) {
                int j = j0 + ct * 16 + c;
#pragma unroll
                for (int r = 0; r < 4; ++r)
                    if (j > irow + r) s[ct][r] = -1e30f;
            }
        }
        // online softmax (base-2 domain; scale folded into Wq)
#pragma unroll
        for (int r = 0; r < 4; ++r) {
            float v = fmaxf(fmaxf(s[0][r], s[1][r]), fmaxf(s[2][r], s[3][r]));
#pragma unroll
            for (int off = 1; off <= 8; off <<= 1)
                v = fmaxf(v, __shfl_xor(v, off));
            float mn = fmaxf(m[r], v);
            float sc = __builtin_amdgcn_exp2f(m[r] - mn);
            m[r] = mn;
            float rs = 0.f;
#pragma unroll
            for (int ct = 0; ct < 4; ++ct) {
                float p = __builtin_amdgcn_exp2f(s[ct][r] - mn);
                s[ct][r] = p;
                rs += p;
            }
#pragma unroll
            for (int off = 1; off <= 8; off <<= 1)
                rs += __shfl_xor(rs, off);
            l[r] = l[r] * sc + rs;
#pragma unroll
            for (int dt = 0; dt < 4; ++dt) o[dt][r] *= sc;
        }
        // P -> LDS (re-layout S frag -> A frag), per-wave private
        __syncthreads();  // protect prior iteration's pa reads
#pragma unroll
        for (int ct = 0; ct < 4; ++ct)
#pragma unroll
            for (int r = 0; r < 4; ++r)
                pl[h * 4 + r][ct * 16 + c] = (__bf16)s[ct][r];
        __syncthreads();
        const bf16x8 pa0 = *(const bf16x8*)(&pl[c][8 * h]);
        const bf16x8 pa1 = *(const bf16x8*)(&pl[c][32 + 8 * h]);
        // O += P V   (B frag from transposed V: contiguous)
#pragma unroll
        for (int dt = 0; dt < 4; ++dt) {
            const __bf16* vp = Vbase + (size_t)(dt * 16 + c) * Tn + j0;
            o[dt] = MFMA16(pa0, *(const bf16x8*)(vp + 8 * h), o[dt]);
            o[dt] = MFMA16(pa1, *(const bf16x8*)(vp + 32 + 8 * h), o[dt]);
        }
    }

    // epilogue: out = O / l  (fp32, row-major [B][T][64])
    float rl[4];
#pragma unroll
    for (int r = 0; r < 4; ++r) rl[r] = 1.0f / l[r];
    float* ob = out + ((size_t)b * Tn + qt * 16) * Hn;
#pragma unroll
    for (int dt = 0; dt < 4; ++dt)
#pragma unroll
        for (int r = 0; r < 4; ++r)
            ob[(h * 4 + r) * Hn + dt * 16 + c] = o[dt][r] * rl[r];
}

// ---------------- launcher -------------------------------------------------
extern "C" void kernel_launch(void* const* d_in, const int* in_sizes, int n_in,
                              void* d_out, int out_size, void* d_ws, size_t ws_size,
                              hipStream_t stream) {
    const float* x  = (const float*)d_in[0];
    const float* Wq = (const float*)d_in[1];
    const float* Wk = (const float*)d_in[2];
    const float* Wv = (const float*)d_in[3];
    float* out = (float*)d_out;

    char* ws = (char*)d_ws;
    __bf16* Wb = (__bf16*)ws;                                  // 3*64*512*2   = 196608 B
    __bf16* Qb = (__bf16*)(ws + 196608);                       // 16384*64*2   = 2097152 B
    __bf16* Kb = (__bf16*)(ws + 196608 + 2097152);             // 2097152 B
    __bf16* VT = (__bf16*)(ws + 196608 + 2 * 2097152);         // 2097152 B

    wconv<<<dim3(128, 3), 256, 0, stream>>>(Wq, Wk, Wv, Wb);
    proj<<<512, 64, 0, stream>>>(x, Wb, Qb, Kb, VT);
    attn<<<1024, 64, 0, stream>>>(Qb, Kb, VT, out);
}

// Round 2
// 105.906 us; speedup vs baseline: 1.5846x; 1.5846x over previous
//
#include <hip/hip_runtime.h>

typedef float f32x4 __attribute__((ext_vector_type(4)));
typedef __bf16 bf16x8 __attribute__((ext_vector_type(8)));
typedef __bf16 bf16x4 __attribute__((ext_vector_type(4)));

#define MFMA16(a, b, c) __builtin_amdgcn_mfma_f32_16x16x32_bf16((a), (b), (c), 0, 0, 0)
// compile-time scheduling fence (no hardware wait)
#define CFENCE() asm volatile("" ::: "memory")
// per-wave LDS write->read fence: DS ops are in-order within a wave; the
// waitcnt guarantees completion, the memory clobber stops compiler reordering.
#define DSFENCE() asm volatile("s_waitcnt lgkmcnt(0)" ::: "memory")

constexpr int Bn = 4, Tn = 4096, Cn = 512, Hn = 64;
// fold C^-0.5 (reference scales by n_embed^-0.5) and log2(e) into Wq.
constexpr float QSCALE = 1.4426950408889634f * 0.04419417382415922f;

// ---------------- kernel 0: W fp32 -> bf16 (Wq pre-scaled) ----------------
__global__ void wconv(const float* __restrict__ Wq, const float* __restrict__ Wk,
                      const float* __restrict__ Wv, __bf16* __restrict__ Wb) {
    int t = blockIdx.y;
    int i = blockIdx.x * 256 + threadIdx.x;  // 0..32767
    const float* src = (t == 0) ? Wq : (t == 1) ? Wk : Wv;
    float scale = (t == 0) ? QSCALE : 1.0f;
    Wb[t * Hn * Cn + i] = (__bf16)(src[i] * scale);
}

__device__ inline bf16x8 cvt8(float4 u0, float4 u1) {
    bf16x8 r;
    r[0] = (__bf16)u0.x; r[1] = (__bf16)u0.y; r[2] = (__bf16)u0.z; r[3] = (__bf16)u0.w;
    r[4] = (__bf16)u1.x; r[5] = (__bf16)u1.y; r[6] = (__bf16)u1.z; r[7] = (__bf16)u1.w;
    return r;
}

// ---------------- kernel 1: fused QKV projection ---------------------------
// 4 waves/block, 16 rows/wave -> 1024 waves. W slices L1-shared in-block.
__global__ __launch_bounds__(256) void proj(const float* __restrict__ x,
                                            const __bf16* __restrict__ Wb,
                                            __bf16* __restrict__ Qb,
                                            __bf16* __restrict__ Kb,
                                            __bf16* __restrict__ VT) {
    const int tid = threadIdx.x;
    const int lane = tid & 63, wid = tid >> 6;
    const int c = lane & 15, h = lane >> 4;
    const int row0 = blockIdx.x * 64 + wid * 16;

    f32x4 acc[3][4] = {};
    const float* xr = x + (size_t)(row0 + c) * Cn;

#pragma unroll
    for (int ks = 0; ks < 16; ++ks) {
        const int kb = ks * 32 + 8 * h;
        const float4* p0 = (const float4*)(xr + kb);
        bf16x8 a0 = cvt8(p0[0], p0[1]);
#pragma unroll
        for (int w = 0; w < 3; ++w)
#pragma unroll
            for (int nt = 0; nt < 4; ++nt) {
                bf16x8 bf = *(const bf16x8*)(Wb + (size_t)(w * Hn + nt * 16 + c) * Cn + kb);
                acc[w][nt] = MFMA16(a0, bf, acc[w][nt]);
            }
    }

    // Q, K epilogue: per-wave LDS transpose -> coalesced row-major stores.
    __shared__ __bf16 lds[4][16][72];
#pragma unroll
    for (int w = 0; w < 2; ++w) {
        CFENCE();
#pragma unroll
        for (int nt = 0; nt < 4; ++nt)
#pragma unroll
            for (int r = 0; r < 4; ++r)
                lds[wid][h * 4 + r][nt * 16 + c] = (__bf16)acc[w][nt][r];
        DSFENCE();
        __bf16* dst = (w == 0) ? Qb : Kb;
#pragma unroll
        for (int ch = 0; ch < 2; ++ch) {
            int rr = ch * 8 + (lane >> 3);
            bf16x8 vv = *(const bf16x8*)(&lds[wid][rr][(lane & 7) * 8]);
            *(bf16x8*)(dst + (size_t)(row0 + rr) * Hn + (lane & 7) * 8) = vv;
        }
        CFENCE();
    }

    // V epilogue: direct transposed store (lane holds 4 consecutive tokens).
    const int b = row0 >> 12;
    const int t0 = row0 & (Tn - 1);
#pragma unroll
    for (int nt = 0; nt < 4; ++nt) {
        f32x4 a = acc[2][nt];
        bf16x4 v4;
        v4[0] = (__bf16)a.x; v4[1] = (__bf16)a.y;
        v4[2] = (__bf16)a.z; v4[3] = (__bf16)a.w;
        *(bf16x4*)(VT + (size_t)(b * Hn + nt * 16 + c) * Tn + t0 + h * 4) = v4;
    }
}

// ---------------- kernel 2: causal flash attention -------------------------
// 512 threads = 8 waves: 2 q-subtiles (16 rows each) x 4-way KV split.
// Per-wave online softmax over its KV slice, then block-level flash merge.
__global__ __launch_bounds__(512) void attn(const __bf16* __restrict__ Qb,
                                            const __bf16* __restrict__ Kb,
                                            const __bf16* __restrict__ VT,
                                            float* __restrict__ out) {
    const int tid = threadIdx.x;
    const int lane = tid & 63, wid = tid >> 6;
    const int c = lane & 15, h = lane >> 4;
    const int qsub = wid >> 2, ws = wid & 3;
    const int qb = (Tn / 32 - 1) - (int)(blockIdx.x >> 2);  // LPT: big tiles first
    const int b = blockIdx.x & 3;
    const int qbase = qb * 32 + qsub * 16;

    const __bf16* Kbase = Kb + (size_t)b * Tn * Hn;
    const __bf16* Vbase = VT + (size_t)b * Hn * Tn;

    const size_t qrow = (size_t)b * Tn + qbase + c;
    const bf16x8 qf0 = *(const bf16x8*)(Qb + qrow * Hn + 8 * h);
    const bf16x8 qf1 = *(const bf16x8*)(Qb + qrow * Hn + 32 + 8 * h);

    f32x4 o[4] = {};
    f32x4 lv = {};                       // row-sum accumulator (via ones-MFMA)
    float m[4] = {-1e30f, -1e30f, -1e30f, -1e30f};

    __shared__ __bf16 pl[8][16][72];     // per-wave P re-layout buffer
    __shared__ float Lo[8][16][64];      // merge: per-wave O
    __shared__ float Lm[8][16];          // merge: per-wave m
    __shared__ float Ll[8][16];          // merge: per-wave l

    bf16x8 ones;
#pragma unroll
    for (int j = 0; j < 8; ++j) ones[j] = (__bf16)1.0f;

    const int nkv = (qbase + 15) / 64 + 1;

    for (int kt = ws; kt < nkv; kt += 4) {
        const int j0 = kt * 64;
        // S = Q K^T  (S frag: col = kv = c, row = q = 4h+r)
        f32x4 s[4];
#pragma unroll
        for (int ct = 0; ct < 4; ++ct) {
            const __bf16* kp = Kbase + (size_t)(j0 + ct * 16 + c) * Hn;
            f32x4 z = {};
            z = MFMA16(qf0, *(const bf16x8*)(kp + 8 * h), z);
            z = MFMA16(qf1, *(const bf16x8*)(kp + 32 + 8 * h), z);
            s[ct] = z;
        }
        // prefetch V fragments (independent of softmax -> hides under VALU)
        bf16x8 vf[4][2];
#pragma unroll
        for (int dt = 0; dt < 4; ++dt) {
            const __bf16* vp = Vbase + (size_t)(dt * 16 + c) * Tn + j0;
            vf[dt][0] = *(const bf16x8*)(vp + 8 * h);
            vf[dt][1] = *(const bf16x8*)(vp + 32 + 8 * h);
        }
        // causal mask (wave-uniform branch, diagonal tiles only)
        if (j0 + 63 > qbase) {
#pragma unroll
            for (int ct = 0; ct < 4; ++ct) {
                int j = j0 + ct * 16 + c;
#pragma unroll
                for (int r = 0; r < 4; ++r)
                    if (j > qbase + h * 4 + r) s[ct][r] = -1e30f;
            }
        }
        // online softmax: row max via shuffles; row sum via ones-MFMA below.
#pragma unroll
        for (int r = 0; r < 4; ++r) {
            float v = fmaxf(fmaxf(s[0][r], s[1][r]), fmaxf(s[2][r], s[3][r]));
#pragma unroll
            for (int off = 1; off <= 8; off <<= 1)
                v = fmaxf(v, __shfl_xor(v, off));
            float mn = fmaxf(m[r], v);
            float sc = __builtin_amdgcn_exp2f(m[r] - mn);
            m[r] = mn;
#pragma unroll
            for (int ct = 0; ct < 4; ++ct)
                s[ct][r] = __builtin_amdgcn_exp2f(s[ct][r] - mn);
            lv[r] *= sc;
#pragma unroll
            for (int dt = 0; dt < 4; ++dt) o[dt][r] *= sc;
        }
        // P -> per-wave LDS (S-frag -> A-frag re-layout); no block barrier.
        CFENCE();
#pragma unroll
        for (int ct = 0; ct < 4; ++ct)
#pragma unroll
            for (int r = 0; r < 4; ++r)
                pl[wid][h * 4 + r][ct * 16 + c] = (__bf16)s[ct][r];
        DSFENCE();
        const bf16x8 pa0 = *(const bf16x8*)(&pl[wid][c][8 * h]);
        const bf16x8 pa1 = *(const bf16x8*)(&pl[wid][c][32 + 8 * h]);
        // row-sum l += P . 1  (replaces 16 shuffles with 2 MFMAs)
        lv = MFMA16(pa0, ones, lv);
        lv = MFMA16(pa1, ones, lv);
        // O += P V
#pragma unroll
        for (int dt = 0; dt < 4; ++dt) {
            o[dt] = MFMA16(pa0, vf[dt][0], o[dt]);
            o[dt] = MFMA16(pa1, vf[dt][1], o[dt]);
        }
        CFENCE();
    }

    // -------- block-level flash merge across the 4 KV-split waves ---------
    if (c == 0) {
#pragma unroll
        for (int r = 0; r < 4; ++r) {
            Lm[wid][h * 4 + r] = m[r];
            Ll[wid][h * 4 + r] = lv[r];
        }
    }
#pragma unroll
    for (int dt = 0; dt < 4; ++dt)
#pragma unroll
        for (int r = 0; r < 4; ++r)
            Lo[wid][h * 4 + r][dt * 16 + c] = o[dt][r];
    __syncthreads();

    const int col = tid & 63;
    const int rg = tid >> 6;
    float* ob = out + ((size_t)b * Tn + qb * 32) * Hn;
#pragma unroll
    for (int rr = 0; rr < 4; ++rr) {
        int row32 = rg * 4 + rr;          // 0..31
        int qs = row32 >> 4, ri = row32 & 15;
        float M = -1e30f;
#pragma unroll
        for (int w = 0; w < 4; ++w) M = fmaxf(M, Lm[qs * 4 + w][ri]);
        float L = 0.f, O = 0.f;
#pragma unroll
        for (int w = 0; w < 4; ++w) {
            float e = __builtin_amdgcn_exp2f(Lm[qs * 4 + w][ri] - M);
            L += Ll[qs * 4 + w][ri] * e;
            O += Lo[qs * 4 + w][ri][col] * e;
        }
        ob[(size_t)row32 * Hn + col] = O / L;
    }
}

// ---------------- launcher -------------------------------------------------
extern "C" void kernel_launch(void* const* d_in, const int* in_sizes, int n_in,
                              void* d_out, int out_size, void* d_ws, size_t ws_size,
                              hipStream_t stream) {
    const float* x  = (const float*)d_in[0];
    const float* Wq = (const float*)d_in[1];
    const float* Wk = (const float*)d_in[2];
    const float* Wv = (const float*)d_in[3];
    float* out = (float*)d_out;

    char* ws = (char*)d_ws;
    __bf16* Wb = (__bf16*)ws;                                  // 196608 B
    __bf16* Qb = (__bf16*)(ws + 196608);                       // 2097152 B
    __bf16* Kb = (__bf16*)(ws + 196608 + 2097152);             // 2097152 B
    __bf16* VT = (__bf16*)(ws + 196608 + 2 * 2097152);         // 2097152 B

    wconv<<<dim3(128, 3), 256, 0, stream>>>(Wq, Wk, Wv, Wb);
    proj<<<256, 256, 0, stream>>>(x, Wb, Qb, Kb, VT);
    attn<<<512, 512, 0, stream>>>(Qb, Kb, VT, out);
}